// Round 3
// baseline (477.070 us; speedup 1.0000x reference)
//
#include <hip/hip_runtime.h>

// (B, D, T, V) = (16, 128, 4096, 1024)
#define B_ 16
#define D_ 128
#define T_ 4096
#define V_ 1024

typedef _Float16 half8 __attribute__((ext_vector_type(8)));
typedef float float4v __attribute__((ext_vector_type(4)));

// ws layout:
//   [0,       4096)   : chsq (V floats) = 0.5*|c|^2
//   [4096,  266240)   : Bh   (4 kt x 1024 v x 32 kk) f16 hi split, MFMA-B-ready
//   [266240,528384)   : Bl   (same, lo split scaled by 2048)

// Fused: split codebook into f16 hi/lo fragments AND compute chsq.
// 16 threads per v, each handling 8 k.
__global__ __launch_bounds__(256) void split_csq_kernel(const float* __restrict__ cb,
                                                        _Float16* __restrict__ Bh,
                                                        _Float16* __restrict__ Bl,
                                                        float* __restrict__ chsq) {
    const int g = blockIdx.x * 256 + threadIdx.x;  // 16384 threads
    const int v = g >> 4;
    const int k0 = (g & 15) << 3;
    const float* src = cb + (size_t)v * D_ + k0;
    half8 h, l;
    float s = 0.f;
#pragma unroll
    for (int j = 0; j < 8; ++j) {
        float c = src[j];
        _Float16 ch = (_Float16)c;
        h[j] = ch;
        l[j] = (_Float16)((c - (float)ch) * 2048.0f);
        s = fmaf(c, c, s);
    }
    const int kt = k0 >> 5;
    const int kk = k0 & 31;
    const size_t off = ((size_t)(kt * V_ + v)) * 32 + kk;
    *(half8*)(Bh + off) = h;
    *(half8*)(Bl + off) = l;
    // reduce |c|^2 over the 16 lanes sharing v (lanes are a contiguous 16-group)
#pragma unroll
    for (int o = 1; o < 16; o <<= 1) s += __shfl_xor(s, o, 64);
    if ((g & 15) == 0) chsq[v] = 0.5f * s;
}

// Main kernel: block = 256 thr = 4 waves; block tile = 64 t x all 1024 v.
// Two-pass per 32-v chunk, single live accumulator set (32 VGPRs):
//   pass P: acc = sum_k xh*ch
//   convert: acc = (acc - chsq)*2048           ( = -2048*score so far )
//   pass R: acc += sum_k (xh*cl' + xl'*ch)     (lo parts pre-scaled by 2048)
//   argMAX acc  ==  argmin score; ties -> lowest v everywhere.
__global__ __launch_bounds__(256, 4) void vq_mfma(const float* __restrict__ latents,
                                                  const float* __restrict__ codebook,
                                                  const float* __restrict__ chsq,
                                                  const _Float16* __restrict__ Bh,
                                                  const _Float16* __restrict__ Bl,
                                                  float* __restrict__ out_codes,
                                                  float* __restrict__ out_q) {
    __shared__ _Float16 Ah[64][136];
    __shared__ _Float16 Al[64][136];
    __shared__ float sbest[4][64];
    __shared__ int sbv[4][64];
    __shared__ int scode[64];

    const int tid = threadIdx.x;
    const int tl = tid & 63;
    const int wq = tid >> 6;
    const int b = blockIdx.x >> 6;
    const int t00 = (blockIdx.x & 63) << 6;

    // ---- stage A tile (64 t x 128 d), f16 split, [t][k] rows, +8 halves pad ----
    {
        const float* xp = latents + (size_t)b * D_ * T_ + t00 + tl;
#pragma unroll
        for (int i = 0; i < 4; ++i) {
            const int d0 = wq * 32 + i * 8;
            float x[8];
#pragma unroll
            for (int j = 0; j < 8; ++j) x[j] = xp[(size_t)(d0 + j) * T_];
            half8 h, l;
#pragma unroll
            for (int j = 0; j < 8; ++j) {
                _Float16 xh = (_Float16)x[j];
                h[j] = xh;
                l[j] = (_Float16)((x[j] - (float)xh) * 2048.0f);
            }
            *(half8*)&Ah[tl][d0] = h;
            *(half8*)&Al[tl][d0] = l;
        }
    }
    __syncthreads();

    const int ln = tid & 15;       // MFMA col (n) / A row (m)
    const int q = (tid >> 4) & 3;  // quad

    float bestF[4][4];
    int bestv[4][4];
#pragma unroll
    for (int mt = 0; mt < 4; ++mt)
#pragma unroll
        for (int r = 0; r < 4; ++r) {
            bestF[mt][r] = -3.0e38f;
            bestv[mt][r] = 0;
        }

    for (int c = 0; c < 8; ++c) {
        const int n0 = wq * 256 + c * 32;
        float4v acc[4][2];
#pragma unroll
        for (int mt = 0; mt < 4; ++mt)
#pragma unroll
            for (int ntl = 0; ntl < 2; ++ntl) acc[mt][ntl] = (float4v){0.f, 0.f, 0.f, 0.f};

        // ---- pass P: xh * ch ----
#pragma unroll
        for (int kt = 0; kt < 4; ++kt) {
            half8 ah[4];
#pragma unroll
            for (int mt = 0; mt < 4; ++mt)
                ah[mt] = *(const half8*)&Ah[mt * 16 + ln][kt * 32 + q * 8];
#pragma unroll
            for (int ntl = 0; ntl < 2; ++ntl) {
                const size_t boff = ((size_t)(kt * V_ + n0 + ntl * 16 + ln)) * 32 + q * 8;
                const half8 bh = *(const half8*)(Bh + boff);
#pragma unroll
                for (int mt = 0; mt < 4; ++mt)
                    acc[mt][ntl] =
                        __builtin_amdgcn_mfma_f32_16x16x32_f16(ah[mt], bh, acc[mt][ntl], 0, 0, 0);
            }
        }
        // ---- convert: acc = (P - chsq) * 2048 ----
#pragma unroll
        for (int ntl = 0; ntl < 2; ++ntl) {
            const float csq = chsq[n0 + ntl * 16 + ln];
#pragma unroll
            for (int mt = 0; mt < 4; ++mt)
#pragma unroll
                for (int r = 0; r < 4; ++r)
                    acc[mt][ntl][r] = (acc[mt][ntl][r] - csq) * 2048.0f;
        }
        // ---- pass R: xh*cl' + xl'*ch ----
#pragma unroll
        for (int kt = 0; kt < 4; ++kt) {
            half8 ah[4], al[4];
#pragma unroll
            for (int mt = 0; mt < 4; ++mt) {
                ah[mt] = *(const half8*)&Ah[mt * 16 + ln][kt * 32 + q * 8];
                al[mt] = *(const half8*)&Al[mt * 16 + ln][kt * 32 + q * 8];
            }
#pragma unroll
            for (int ntl = 0; ntl < 2; ++ntl) {
                const size_t boff = ((size_t)(kt * V_ + n0 + ntl * 16 + ln)) * 32 + q * 8;
                const half8 bh = *(const half8*)(Bh + boff);
                const half8 bl = *(const half8*)(Bl + boff);
#pragma unroll
                for (int mt = 0; mt < 4; ++mt) {
                    acc[mt][ntl] =
                        __builtin_amdgcn_mfma_f32_16x16x32_f16(ah[mt], bl, acc[mt][ntl], 0, 0, 0);
                    acc[mt][ntl] =
                        __builtin_amdgcn_mfma_f32_16x16x32_f16(al[mt], bh, acc[mt][ntl], 0, 0, 0);
                }
            }
        }
        // ---- fold into running argmax (F = -2048*score); ntl=0 first => lower n ----
#pragma unroll
        for (int ntl = 0; ntl < 2; ++ntl) {
            const int n = n0 + ntl * 16 + ln;
#pragma unroll
            for (int mt = 0; mt < 4; ++mt)
#pragma unroll
                for (int r = 0; r < 4; ++r) {
                    const float f = acc[mt][ntl][r];
                    if (f > bestF[mt][r]) {  // strict > keeps lowest v on exact ties
                        bestF[mt][r] = f;
                        bestv[mt][r] = n;
                    }
                }
        }
    }

    // cross-lane argmax over the 16-col group; ties -> lowest v
#pragma unroll
    for (int off = 1; off < 16; off <<= 1) {
#pragma unroll
        for (int mt = 0; mt < 4; ++mt)
#pragma unroll
            for (int r = 0; r < 4; ++r) {
                const float of = __shfl_xor(bestF[mt][r], off, 64);
                const int ov = __shfl_xor(bestv[mt][r], off, 64);
                if (of > bestF[mt][r] || (of == bestF[mt][r] && ov < bestv[mt][r])) {
                    bestF[mt][r] = of;
                    bestv[mt][r] = ov;
                }
            }
    }

    if (ln == 0) {
#pragma unroll
        for (int mt = 0; mt < 4; ++mt)
#pragma unroll
            for (int r = 0; r < 4; ++r) {
                const int m = mt * 16 + q * 4 + r;
                sbest[wq][m] = bestF[mt][r];
                sbv[wq][m] = bestv[mt][r];
            }
    }
    __syncthreads();

    if (tid < 64) {
        float bb = sbest[0][tid];
        int bv = sbv[0][tid];
#pragma unroll
        for (int w = 1; w < 4; ++w) {
            const float of = sbest[w][tid];
            const int ov = sbv[w][tid];
            if (of > bb) {  // waves ascend in v; strict > keeps lowest v on ties
                bb = of;
                bv = ov;
            }
        }
        scode[tid] = bv;
        out_codes[(size_t)b * T_ + t00 + tid] = (float)bv;
    }
    __syncthreads();

    // gather-write quantized[b, d, t00+tl] = codebook[code, d]; coalesced 256B stores
    const int code = scode[tl];
    const float* crow = codebook + (size_t)code * D_;
    float* qp = out_q + (size_t)b * D_ * T_ + t00 + tl;
#pragma unroll
    for (int i = 0; i < 32; ++i) {
        const int d = wq * 32 + i;
        qp[(size_t)d * T_] = crow[d];
    }
}

extern "C" void kernel_launch(void* const* d_in, const int* in_sizes, int n_in,
                              void* d_out, int out_size, void* d_ws, size_t ws_size,
                              hipStream_t stream) {
    const float* latents = (const float*)d_in[0];   // (B, D, T) f32
    const float* codebook = (const float*)d_in[1];  // (V, D) f32

    float* out_codes = (float*)d_out;        // (B, T) codes as f32 values
    float* out_q = (float*)d_out + B_ * T_;  // (B, D, T) quantized f32

    float* chsq = (float*)d_ws;
    _Float16* Bh = (_Float16*)((char*)d_ws + 4096);
    _Float16* Bl = (_Float16*)((char*)d_ws + 4096 + 262144);

    split_csq_kernel<<<(V_ * 16) / 256, 256, 0, stream>>>(codebook, Bh, Bl, chsq);
    vq_mfma<<<(B_ * T_) / 64, 256, 0, stream>>>(latents, codebook, chsq, Bh, Bl, out_codes,
                                                out_q);
}

// Round 4
// 316.349 us; speedup vs baseline: 1.5080x; 1.5080x over previous
//
#include <hip/hip_runtime.h>

// (B, D, T, V) = (16, 128, 4096, 1024)
#define B_ 16
#define D_ 128
#define T_ 4096
#define V_ 1024

typedef _Float16 half8 __attribute__((ext_vector_type(8)));
typedef float float4v __attribute__((ext_vector_type(4)));

// ws layout:
//   [0,       4096)   : chsq (V floats) = 0.5*|c|^2
//   [4096,  266240)   : Bh   (4 kt x 1024 v x 32 kk) f16 hi split, MFMA-B-ready
//   [266240,528384)   : Bl   (same, lo split scaled by 2048)

// Fused: split codebook into f16 hi/lo fragments AND compute chsq.
__global__ __launch_bounds__(256) void split_csq_kernel(const float* __restrict__ cb,
                                                        _Float16* __restrict__ Bh,
                                                        _Float16* __restrict__ Bl,
                                                        float* __restrict__ chsq) {
    const int g = blockIdx.x * 256 + threadIdx.x;  // 16384 threads
    const int v = g >> 4;
    const int k0 = (g & 15) << 3;
    const float* src = cb + (size_t)v * D_ + k0;
    half8 h, l;
    float s = 0.f;
#pragma unroll
    for (int j = 0; j < 8; ++j) {
        float c = src[j];
        _Float16 ch = (_Float16)c;
        h[j] = ch;
        l[j] = (_Float16)((c - (float)ch) * 2048.0f);
        s = fmaf(c, c, s);
    }
    const int kt = k0 >> 5;
    const int kk = k0 & 31;
    const size_t off = ((size_t)(kt * V_ + v)) * 32 + kk;
    *(half8*)(Bh + off) = h;
    *(half8*)(Bl + off) = l;
#pragma unroll
    for (int o = 1; o < 16; o <<= 1) s += __shfl_xor(s, o, 64);
    if ((g & 15) == 0) chsq[v] = 0.5f * s;
}

// Main kernel: block = 256 thr = 4 waves; block tile = 64 t x all 1024 v.
// Two-pass per 32-v chunk, single live accumulator set (32 VGPRs):
//   pass P: acc = sum_k xh*ch           (all 8 B-frags hoisted before kt loop)
//   convert: acc = (acc - chsq)*2048    ( = -2048*score so far )
//   pass R: acc += sum_k (xh*cl' + xl'*ch)
//   argMAX acc == argmin score; ties -> lowest v everywhere.
// launch_bounds(256,3): 3 waves/SIMD budget ~170 VGPR. (256,4) spilled to
// scratch (R3: FETCH 853MB, WRITE 388MB) — do not tighten without checking
// FETCH/WRITE for the spill signature.
__global__ __launch_bounds__(256, 3) void vq_mfma(const float* __restrict__ latents,
                                                  const float* __restrict__ codebook,
                                                  const float* __restrict__ chsq,
                                                  const _Float16* __restrict__ Bh,
                                                  const _Float16* __restrict__ Bl,
                                                  float* __restrict__ out_codes,
                                                  float* __restrict__ out_q) {
    __shared__ _Float16 Ah[64][136];
    __shared__ _Float16 Al[64][136];
    __shared__ float sbest[4][64];
    __shared__ int sbv[4][64];
    __shared__ int scode[64];

    const int tid = threadIdx.x;
    const int tl = tid & 63;
    const int wq = tid >> 6;
    const int b = blockIdx.x >> 6;
    const int t00 = (blockIdx.x & 63) << 6;

    // ---- stage A tile (64 t x 128 d), f16 split, [t][k] rows, +8 halves pad ----
    {
        const float* xp = latents + (size_t)b * D_ * T_ + t00 + tl;
#pragma unroll
        for (int i = 0; i < 4; ++i) {
            const int d0 = wq * 32 + i * 8;
            float x[8];
#pragma unroll
            for (int j = 0; j < 8; ++j) x[j] = xp[(size_t)(d0 + j) * T_];
            half8 h, l;
#pragma unroll
            for (int j = 0; j < 8; ++j) {
                _Float16 xh = (_Float16)x[j];
                h[j] = xh;
                l[j] = (_Float16)((x[j] - (float)xh) * 2048.0f);
            }
            *(half8*)&Ah[tl][d0] = h;
            *(half8*)&Al[tl][d0] = l;
        }
    }
    __syncthreads();

    const int ln = tid & 15;       // MFMA col (n) / A row (m)
    const int q = (tid >> 4) & 3;  // quad

    float bestF[4][4];
    int bestv[4][4];
#pragma unroll
    for (int mt = 0; mt < 4; ++mt)
#pragma unroll
        for (int r = 0; r < 4; ++r) {
            bestF[mt][r] = -3.0e38f;
            bestv[mt][r] = 0;
        }

    for (int c = 0; c < 8; ++c) {
        const int n0 = wq * 256 + c * 32;
        float4v acc[4][2];
#pragma unroll
        for (int mt = 0; mt < 4; ++mt)
#pragma unroll
            for (int ntl = 0; ntl < 2; ++ntl) acc[mt][ntl] = (float4v){0.f, 0.f, 0.f, 0.f};

        // ---- pass P: xh * ch. Hoist ALL 8 B-frags (32 VGPRs) so the L2
        //      latency overlaps the LDS reads + MFMAs below. ----
        half8 bhp[4][2];
#pragma unroll
        for (int kt = 0; kt < 4; ++kt)
#pragma unroll
            for (int ntl = 0; ntl < 2; ++ntl)
                bhp[kt][ntl] =
                    *(const half8*)(Bh + ((size_t)(kt * V_ + n0 + ntl * 16 + ln)) * 32 + q * 8);
#pragma unroll
        for (int kt = 0; kt < 4; ++kt) {
            half8 ah[4];
#pragma unroll
            for (int mt = 0; mt < 4; ++mt)
                ah[mt] = *(const half8*)&Ah[mt * 16 + ln][kt * 32 + q * 8];
#pragma unroll
            for (int ntl = 0; ntl < 2; ++ntl)
#pragma unroll
                for (int mt = 0; mt < 4; ++mt)
                    acc[mt][ntl] = __builtin_amdgcn_mfma_f32_16x16x32_f16(ah[mt], bhp[kt][ntl],
                                                                          acc[mt][ntl], 0, 0, 0);
        }
        // ---- convert: acc = (P - chsq) * 2048 ----
#pragma unroll
        for (int ntl = 0; ntl < 2; ++ntl) {
            const float csq = chsq[n0 + ntl * 16 + ln];
#pragma unroll
            for (int mt = 0; mt < 4; ++mt)
#pragma unroll
                for (int r = 0; r < 4; ++r)
                    acc[mt][ntl][r] = (acc[mt][ntl][r] - csq) * 2048.0f;
        }
        // ---- pass R: xh*cl' + xl'*ch ----
#pragma unroll
        for (int kt = 0; kt < 4; ++kt) {
            half8 bl2[2], bh2[2];
#pragma unroll
            for (int ntl = 0; ntl < 2; ++ntl) {
                const size_t boff = ((size_t)(kt * V_ + n0 + ntl * 16 + ln)) * 32 + q * 8;
                bl2[ntl] = *(const half8*)(Bl + boff);
                bh2[ntl] = *(const half8*)(Bh + boff);
            }
            half8 ah[4], al[4];
#pragma unroll
            for (int mt = 0; mt < 4; ++mt) {
                ah[mt] = *(const half8*)&Ah[mt * 16 + ln][kt * 32 + q * 8];
                al[mt] = *(const half8*)&Al[mt * 16 + ln][kt * 32 + q * 8];
            }
#pragma unroll
            for (int ntl = 0; ntl < 2; ++ntl)
#pragma unroll
                for (int mt = 0; mt < 4; ++mt) {
                    acc[mt][ntl] =
                        __builtin_amdgcn_mfma_f32_16x16x32_f16(ah[mt], bl2[ntl], acc[mt][ntl], 0, 0, 0);
                    acc[mt][ntl] =
                        __builtin_amdgcn_mfma_f32_16x16x32_f16(al[mt], bh2[ntl], acc[mt][ntl], 0, 0, 0);
                }
        }
        // ---- fold into running argmax (F = -2048*score); ntl=0 first => lower n ----
#pragma unroll
        for (int ntl = 0; ntl < 2; ++ntl) {
            const int n = n0 + ntl * 16 + ln;
#pragma unroll
            for (int mt = 0; mt < 4; ++mt)
#pragma unroll
                for (int r = 0; r < 4; ++r) {
                    const float f = acc[mt][ntl][r];
                    if (f > bestF[mt][r]) {  // strict > keeps lowest v on exact ties
                        bestF[mt][r] = f;
                        bestv[mt][r] = n;
                    }
                }
        }
    }

    // cross-lane argmax over the 16-col group; ties -> lowest v
#pragma unroll
    for (int off = 1; off < 16; off <<= 1) {
#pragma unroll
        for (int mt = 0; mt < 4; ++mt)
#pragma unroll
            for (int r = 0; r < 4; ++r) {
                const float of = __shfl_xor(bestF[mt][r], off, 64);
                const int ov = __shfl_xor(bestv[mt][r], off, 64);
                if (of > bestF[mt][r] || (of == bestF[mt][r] && ov < bestv[mt][r])) {
                    bestF[mt][r] = of;
                    bestv[mt][r] = ov;
                }
            }
    }

    if (ln == 0) {
#pragma unroll
        for (int mt = 0; mt < 4; ++mt)
#pragma unroll
            for (int r = 0; r < 4; ++r) {
                const int m = mt * 16 + q * 4 + r;
                sbest[wq][m] = bestF[mt][r];
                sbv[wq][m] = bestv[mt][r];
            }
    }
    __syncthreads();

    if (tid < 64) {
        float bb = sbest[0][tid];
        int bv = sbv[0][tid];
#pragma unroll
        for (int w = 1; w < 4; ++w) {
            const float of = sbest[w][tid];
            const int ov = sbv[w][tid];
            if (of > bb) {  // waves ascend in v; strict > keeps lowest v on ties
                bb = of;
                bv = ov;
            }
        }
        scode[tid] = bv;
        out_codes[(size_t)b * T_ + t00 + tid] = (float)bv;
    }
    __syncthreads();

    // gather-write quantized[b, d, t00+tl] = codebook[code, d]; coalesced 256B stores
    const int code = scode[tl];
    const float* crow = codebook + (size_t)code * D_;
    float* qp = out_q + (size_t)b * D_ * T_ + t00 + tl;
#pragma unroll
    for (int i = 0; i < 32; ++i) {
        const int d = wq * 32 + i;
        qp[(size_t)d * T_] = crow[d];
    }
}

extern "C" void kernel_launch(void* const* d_in, const int* in_sizes, int n_in,
                              void* d_out, int out_size, void* d_ws, size_t ws_size,
                              hipStream_t stream) {
    const float* latents = (const float*)d_in[0];   // (B, D, T) f32
    const float* codebook = (const float*)d_in[1];  // (V, D) f32

    float* out_codes = (float*)d_out;        // (B, T) codes as f32 values
    float* out_q = (float*)d_out + B_ * T_;  // (B, D, T) quantized f32

    float* chsq = (float*)d_ws;
    _Float16* Bh = (_Float16*)((char*)d_ws + 4096);
    _Float16* Bl = (_Float16*)((char*)d_ws + 4096 + 262144);

    split_csq_kernel<<<(V_ * 16) / 256, 256, 0, stream>>>(codebook, Bh, Bl, chsq);
    vq_mfma<<<(B_ * T_) / 64, 256, 0, stream>>>(latents, codebook, chsq, Bh, Bl, out_codes,
                                                out_q);
}

// Round 6
// 193.864 us; speedup vs baseline: 2.4608x; 1.6318x over previous
//
#include <hip/hip_runtime.h>

// (B, D, T, V) = (16, 128, 4096, 1024)
#define B_ 16
#define D_ 128
#define T_ 4096
#define V_ 1024

typedef _Float16 half8 __attribute__((ext_vector_type(8)));
typedef float float4v __attribute__((ext_vector_type(4)));

// ws layout:
//   [0,       4096)   : chsq (V floats) = 0.5*|c|^2
//   [4096,  266240)   : Bh   (4 kt x 1024 v x 32 kk) f16 hi split, MFMA-B-ready
//   [266240,528384)   : Bl   (same, lo split scaled by 2048)
//
// LESSONS:
//  R3/R4: VGPR_Count is the ARCH half of the unified file; forcing
//    __launch_bounds__(256,{3,4}) on the mt=4 tile (64 AGPR acc + ~130
//    arch-live) spills through HBM (FETCH 356-853MB signature).
//  R5: hipLaunchCooperativeKernel silently no-ops under this harness —
//    plain launches only.
//  This round: mt=2 wave tile cuts acc to 32 AGPR / arch-live ~100 so
//    (256,3) fits honestly.

// Fused: split codebook into f16 hi/lo fragments AND compute chsq.
__global__ __launch_bounds__(256) void split_csq_kernel(const float* __restrict__ cb,
                                                        _Float16* __restrict__ Bh,
                                                        _Float16* __restrict__ Bl,
                                                        float* __restrict__ chsq) {
    const int g = blockIdx.x * 256 + threadIdx.x;  // 16384 threads
    const int v = g >> 4;
    const int k0 = (g & 15) << 3;
    const float* src = cb + (size_t)v * D_ + k0;
    half8 h, l;
    float s = 0.f;
#pragma unroll
    for (int j = 0; j < 8; ++j) {
        float c = src[j];
        _Float16 ch = (_Float16)c;
        h[j] = ch;
        l[j] = (_Float16)((c - (float)ch) * 2048.0f);
        s = fmaf(c, c, s);
    }
    const int kt = k0 >> 5;
    const int kk = k0 & 31;
    const size_t off = ((size_t)(kt * V_ + v)) * 32 + kk;
    *(half8*)(Bh + off) = h;
    *(half8*)(Bl + off) = l;
#pragma unroll
    for (int o = 1; o < 16; o <<= 1) s += __shfl_xor(s, o, 64);
    if ((g & 15) == 0) chsq[v] = 0.5f * s;
}

// Main kernel: block = 256 thr = 4 waves; block tile = 64 t x all 1024 v.
// Wave (wm, wn) computes a 32t x 512v sub-tile: mt=2 m-tiles, 16 chunks of 32v.
// Dual accumulators (numerics proven in R2, absmax 0):
//   acc1 = sum_k xh*ch ; acc2 = sum_k (xh*cl' + xl'*ch)   (lo pre-scaled 2048)
//   score = 0.5|c|^2 - (acc1 + acc2/2048); running argmin, ties -> lowest v.
__global__ __launch_bounds__(256, 3) void vq_mfma(const float* __restrict__ latents,
                                                  const float* __restrict__ codebook,
                                                  const float* __restrict__ chsq,
                                                  const _Float16* __restrict__ Bh,
                                                  const _Float16* __restrict__ Bl,
                                                  float* __restrict__ out_codes,
                                                  float* __restrict__ out_q) {
    __shared__ _Float16 Ah[64][136];
    __shared__ _Float16 Al[64][136];
    __shared__ float sbest[2][64];
    __shared__ int sbv[2][64];
    __shared__ int scode[64];

    const int tid = threadIdx.x;
    const int tl = tid & 63;
    const int wq = tid >> 6;
    const int wm = wq >> 1;   // t-half (0: rows 0-31, 1: rows 32-63)
    const int wn = wq & 1;    // v-half (0: v 0-511, 1: v 512-1023)
    const int b = blockIdx.x >> 6;
    const int t00 = (blockIdx.x & 63) << 6;

    // ---- stage A tile (64 t x 128 d), f16 split, [t][k] rows, +8 pad ----
    {
        const float* xp = latents + (size_t)b * D_ * T_ + t00 + tl;
#pragma unroll
        for (int i = 0; i < 4; ++i) {
            const int d0 = wq * 32 + i * 8;
            float x[8];
#pragma unroll
            for (int j = 0; j < 8; ++j) x[j] = xp[(size_t)(d0 + j) * T_];
            half8 h, l;
#pragma unroll
            for (int j = 0; j < 8; ++j) {
                _Float16 xh = (_Float16)x[j];
                h[j] = xh;
                l[j] = (_Float16)((x[j] - (float)xh) * 2048.0f);
            }
            *(half8*)&Ah[tl][d0] = h;
            *(half8*)&Al[tl][d0] = l;
        }
    }
    __syncthreads();

    const int ln = tid & 15;       // MFMA col (n) / A row (m)
    const int q = (tid >> 4) & 3;  // quad

    float bestF[2][4];
    int bestv[2][4];
#pragma unroll
    for (int mt = 0; mt < 2; ++mt)
#pragma unroll
        for (int r = 0; r < 4; ++r) {
            bestF[mt][r] = 3.0e38f;
            bestv[mt][r] = 0;
        }

    for (int c = 0; c < 16; ++c) {
        const int n0 = wn * 512 + c * 32;
        float4v acc1[2][2], acc2[2][2];
#pragma unroll
        for (int mt = 0; mt < 2; ++mt)
#pragma unroll
            for (int ntl = 0; ntl < 2; ++ntl) {
                acc1[mt][ntl] = (float4v){0.f, 0.f, 0.f, 0.f};
                acc2[mt][ntl] = (float4v){0.f, 0.f, 0.f, 0.f};
            }
#pragma unroll
        for (int kt = 0; kt < 4; ++kt) {
            half8 bh[2], bl[2];
#pragma unroll
            for (int ntl = 0; ntl < 2; ++ntl) {
                const size_t boff = ((size_t)(kt * V_ + n0 + ntl * 16 + ln)) * 32 + q * 8;
                bh[ntl] = *(const half8*)(Bh + boff);
                bl[ntl] = *(const half8*)(Bl + boff);
            }
            half8 ah[2], al[2];
#pragma unroll
            for (int mt = 0; mt < 2; ++mt) {
                const int row = wm * 32 + mt * 16 + ln;
                ah[mt] = *(const half8*)&Ah[row][kt * 32 + q * 8];
                al[mt] = *(const half8*)&Al[row][kt * 32 + q * 8];
            }
#pragma unroll
            for (int ntl = 0; ntl < 2; ++ntl)
#pragma unroll
                for (int mt = 0; mt < 2; ++mt) {
                    acc1[mt][ntl] = __builtin_amdgcn_mfma_f32_16x16x32_f16(
                        ah[mt], bh[ntl], acc1[mt][ntl], 0, 0, 0);
                    acc2[mt][ntl] = __builtin_amdgcn_mfma_f32_16x16x32_f16(
                        ah[mt], bl[ntl], acc2[mt][ntl], 0, 0, 0);
                    acc2[mt][ntl] = __builtin_amdgcn_mfma_f32_16x16x32_f16(
                        al[mt], bh[ntl], acc2[mt][ntl], 0, 0, 0);
                }
        }
        // fold scores into running argmin (ntl=0 first: lower n wins ties)
#pragma unroll
        for (int ntl = 0; ntl < 2; ++ntl) {
            const int n = n0 + ntl * 16 + ln;
            const float csq = chsq[n];
#pragma unroll
            for (int mt = 0; mt < 2; ++mt)
#pragma unroll
                for (int r = 0; r < 4; ++r) {
                    const float score =
                        csq - (acc1[mt][ntl][r] + acc2[mt][ntl][r] * (1.0f / 2048.0f));
                    if (score < bestF[mt][r]) {  // strict < => lowest v on ties
                        bestF[mt][r] = score;
                        bestv[mt][r] = n;
                    }
                }
        }
    }

    // cross-lane argmin over the 16-col group; ties -> lowest v
#pragma unroll
    for (int off = 1; off < 16; off <<= 1) {
#pragma unroll
        for (int mt = 0; mt < 2; ++mt)
#pragma unroll
            for (int r = 0; r < 4; ++r) {
                const float of = __shfl_xor(bestF[mt][r], off, 64);
                const int ov = __shfl_xor(bestv[mt][r], off, 64);
                if (of < bestF[mt][r] || (of == bestF[mt][r] && ov < bestv[mt][r])) {
                    bestF[mt][r] = of;
                    bestv[mt][r] = ov;
                }
            }
    }

    if (ln == 0) {
#pragma unroll
        for (int mt = 0; mt < 2; ++mt)
#pragma unroll
            for (int r = 0; r < 4; ++r) {
                const int m = wm * 32 + mt * 16 + q * 4 + r;
                sbest[wn][m] = bestF[mt][r];
                sbv[wn][m] = bestv[mt][r];
            }
    }
    __syncthreads();

    if (tid < 64) {
        float bb = sbest[0][tid];  // wn=0 = lower v half: wins ties via strict <
        int bv = sbv[0][tid];
        const float of = sbest[1][tid];
        const int ov = sbv[1][tid];
        if (of < bb) {
            bb = of;
            bv = ov;
        }
        scode[tid] = bv;
        out_codes[(size_t)b * T_ + t00 + tid] = (float)bv;
    }
    __syncthreads();

    // gather-write quantized[b, d, t00+tl] = codebook[code, d]; coalesced stores
    const int code = scode[tl];
    const float* crow = codebook + (size_t)code * D_;
    float* qp = out_q + (size_t)b * D_ * T_ + t00 + tl;
#pragma unroll
    for (int i = 0; i < 32; ++i) {
        const int d = wq * 32 + i;
        qp[(size_t)d * T_] = crow[d];
    }
}

extern "C" void kernel_launch(void* const* d_in, const int* in_sizes, int n_in,
                              void* d_out, int out_size, void* d_ws, size_t ws_size,
                              hipStream_t stream) {
    const float* latents = (const float*)d_in[0];   // (B, D, T) f32
    const float* codebook = (const float*)d_in[1];  // (V, D) f32

    float* out_codes = (float*)d_out;        // (B, T) codes as f32 values
    float* out_q = (float*)d_out + B_ * T_;  // (B, D, T) quantized f32

    float* chsq = (float*)d_ws;
    _Float16* Bh = (_Float16*)((char*)d_ws + 4096);
    _Float16* Bl = (_Float16*)((char*)d_ws + 4096 + 262144);

    split_csq_kernel<<<(V_ * 16) / 256, 256, 0, stream>>>(codebook, Bh, Bl, chsq);
    vq_mfma<<<(B_ * T_) / 64, 256, 0, stream>>>(latents, codebook, chsq, Bh, Bl, out_codes,
                                                out_q);
}

// Round 7
// 154.726 us; speedup vs baseline: 3.0833x; 1.2530x over previous
//
#include <hip/hip_runtime.h>

// (B, D, T, V) = (16, 128, 4096, 1024)
#define B_ 16
#define D_ 128
#define T_ 4096
#define V_ 1024

typedef _Float16 half8 __attribute__((ext_vector_type(8)));
typedef float float4v __attribute__((ext_vector_type(4)));

// ws layout:
//   [0,       4096)   : chsq (V floats) = 0.5*|c|^2
//   [4096,  266240)   : Bh   (4 kt x 1024 v x 32 kk) f16 hi split, MFMA-B-ready
//   [266240,528384)   : Bl   (same, lo split scaled by 2048)
//
// LESSONS:
//  R3/R4: forcing __launch_bounds__(256,{3,4}) spills accumulators through HBM
//    (FETCH 356-853MB signature). (256,2) is the no-spill point for mt=4.
//  R5: hipLaunchCooperativeKernel fails under this harness — plain launches.
//  R6: occupancy cannot be raised honestly (mt=2 @ (256,3) stayed ~2 blocks/CU
//    and regressed 109->127us). Latency must be hidden with in-wave ILP.
//  R7: B-fragment software pipeline (cur/nxt rotation) on the R2 structure.

// Fused: split codebook into f16 hi/lo fragments AND compute chsq.
__global__ __launch_bounds__(256) void split_csq_kernel(const float* __restrict__ cb,
                                                        _Float16* __restrict__ Bh,
                                                        _Float16* __restrict__ Bl,
                                                        float* __restrict__ chsq) {
    const int g = blockIdx.x * 256 + threadIdx.x;  // 16384 threads
    const int v = g >> 4;
    const int k0 = (g & 15) << 3;
    const float* src = cb + (size_t)v * D_ + k0;
    half8 h, l;
    float s = 0.f;
#pragma unroll
    for (int j = 0; j < 8; ++j) {
        float c = src[j];
        _Float16 ch = (_Float16)c;
        h[j] = ch;
        l[j] = (_Float16)((c - (float)ch) * 2048.0f);
        s = fmaf(c, c, s);
    }
    const int kt = k0 >> 5;
    const int kk = k0 & 31;
    const size_t off = ((size_t)(kt * V_ + v)) * 32 + kk;
    *(half8*)(Bh + off) = h;
    *(half8*)(Bl + off) = l;
#pragma unroll
    for (int o = 1; o < 16; o <<= 1) s += __shfl_xor(s, o, 64);
    if ((g & 15) == 0) chsq[v] = 0.5f * s;
}

// Main kernel: block = 256 thr = 4 waves; block tile = 64 t x all 1024 v.
// Wave wq sweeps v in [wq*256, wq*256+256) in 8 chunks of 32 (2 n-tiles), mt=4.
// Dual accumulators (numerics proven: absmax 0):
//   acc1 = sum_k xh*ch ; acc2 = sum_k (xh*cl' + xl'*ch)  (lo pre-scaled 2048)
//   score = 0.5|c|^2 - (acc1 + acc2/2048); running argmin, ties -> lowest v.
// B fragments are software-pipelined one kt-step ahead (cur/nxt rotation) so
// the ~200-400cyc L2 latency overlaps the MFMA burst of the previous step.
__global__ __launch_bounds__(256, 2) void vq_mfma(const float* __restrict__ latents,
                                                  const float* __restrict__ codebook,
                                                  const float* __restrict__ chsq,
                                                  const _Float16* __restrict__ Bh,
                                                  const _Float16* __restrict__ Bl,
                                                  float* __restrict__ out_codes,
                                                  float* __restrict__ out_q) {
    __shared__ _Float16 Ah[64][136];
    __shared__ _Float16 Al[64][136];
    __shared__ float sbest[4][64];
    __shared__ int sbv[4][64];
    __shared__ int scode[64];

    const int tid = threadIdx.x;
    const int tl = tid & 63;
    const int wq = tid >> 6;
    const int b = blockIdx.x >> 6;
    const int t00 = (blockIdx.x & 63) << 6;

    // ---- stage A tile (64 t x 128 d), f16 split, [t][k] rows, +8 pad ----
    {
        const float* xp = latents + (size_t)b * D_ * T_ + t00 + tl;
#pragma unroll
        for (int i = 0; i < 4; ++i) {
            const int d0 = wq * 32 + i * 8;
            float x[8];
#pragma unroll
            for (int j = 0; j < 8; ++j) x[j] = xp[(size_t)(d0 + j) * T_];
            half8 h, l;
#pragma unroll
            for (int j = 0; j < 8; ++j) {
                _Float16 xh = (_Float16)x[j];
                h[j] = xh;
                l[j] = (_Float16)((x[j] - (float)xh) * 2048.0f);
            }
            *(half8*)&Ah[tl][d0] = h;
            *(half8*)&Al[tl][d0] = l;
        }
    }
    __syncthreads();

    const int ln = tid & 15;       // MFMA col (n) / A row (m)
    const int q = (tid >> 4) & 3;  // quad
    const int v0 = wq * 256;

    float bestF[4][4];
    int bestv[4][4];
#pragma unroll
    for (int mt = 0; mt < 4; ++mt)
#pragma unroll
        for (int r = 0; r < 4; ++r) {
            bestF[mt][r] = 3.0e38f;
            bestv[mt][r] = 0;
        }

    // B-fragment byte offset for (n0, kt, ntl), per-lane
    auto boff = [&](int n0, int kt, int ntl) -> size_t {
        return ((size_t)(kt * V_ + n0 + ntl * 16 + ln)) * 32 + (size_t)q * 8;
    };

    // ---- pipeline prologue: load (c=0, kt=0) fragments ----
    half8 bh_cur[2], bl_cur[2];
#pragma unroll
    for (int ntl = 0; ntl < 2; ++ntl) {
        const size_t o = boff(v0, 0, ntl);
        bh_cur[ntl] = *(const half8*)(Bh + o);
        bl_cur[ntl] = *(const half8*)(Bl + o);
    }

    for (int c = 0; c < 8; ++c) {
        const int n0 = v0 + c * 32;
        float4v acc1[4][2], acc2[4][2];
#pragma unroll
        for (int mt = 0; mt < 4; ++mt)
#pragma unroll
            for (int ntl = 0; ntl < 2; ++ntl) {
                acc1[mt][ntl] = (float4v){0.f, 0.f, 0.f, 0.f};
                acc2[mt][ntl] = (float4v){0.f, 0.f, 0.f, 0.f};
            }
#pragma unroll
        for (int kt = 0; kt < 4; ++kt) {
            // ---- prefetch next step's B fragments (kt+1, or next chunk's kt=0;
            //      wraps to chunk 0 on the final step — harmless reload) ----
            const int kt2 = (kt + 1) & 3;
            const int n0_2 = (kt == 3) ? (v0 + ((c + 1) & 7) * 32) : n0;
            half8 bh_nxt[2], bl_nxt[2];
#pragma unroll
            for (int ntl = 0; ntl < 2; ++ntl) {
                const size_t o = boff(n0_2, kt2, ntl);
                bh_nxt[ntl] = *(const half8*)(Bh + o);
                bl_nxt[ntl] = *(const half8*)(Bl + o);
            }
            // ---- A fragments from LDS (fine-grained lgkmcnt, low latency) ----
            half8 ah[4], al[4];
#pragma unroll
            for (int mt = 0; mt < 4; ++mt) {
                ah[mt] = *(const half8*)&Ah[mt * 16 + ln][kt * 32 + q * 8];
                al[mt] = *(const half8*)&Al[mt * 16 + ln][kt * 32 + q * 8];
            }
            // ---- MFMA burst consumes cur (loaded one step ago) ----
#pragma unroll
            for (int ntl = 0; ntl < 2; ++ntl)
#pragma unroll
                for (int mt = 0; mt < 4; ++mt) {
                    acc1[mt][ntl] = __builtin_amdgcn_mfma_f32_16x16x32_f16(
                        ah[mt], bh_cur[ntl], acc1[mt][ntl], 0, 0, 0);
                    acc2[mt][ntl] = __builtin_amdgcn_mfma_f32_16x16x32_f16(
                        ah[mt], bl_cur[ntl], acc2[mt][ntl], 0, 0, 0);
                    acc2[mt][ntl] = __builtin_amdgcn_mfma_f32_16x16x32_f16(
                        al[mt], bh_cur[ntl], acc2[mt][ntl], 0, 0, 0);
                }
            // ---- rotate (SSA under full unroll; 16 loop-carried VGPRs at c-edge) ----
#pragma unroll
            for (int ntl = 0; ntl < 2; ++ntl) {
                bh_cur[ntl] = bh_nxt[ntl];
                bl_cur[ntl] = bl_nxt[ntl];
            }
        }
        // fold scores into running argmin (ntl=0 first: lower n wins ties)
#pragma unroll
        for (int ntl = 0; ntl < 2; ++ntl) {
            const int n = n0 + ntl * 16 + ln;
            const float csq = chsq[n];
#pragma unroll
            for (int mt = 0; mt < 4; ++mt)
#pragma unroll
                for (int r = 0; r < 4; ++r) {
                    const float score =
                        csq - (acc1[mt][ntl][r] + acc2[mt][ntl][r] * (1.0f / 2048.0f));
                    if (score < bestF[mt][r]) {  // strict < => lowest v on ties
                        bestF[mt][r] = score;
                        bestv[mt][r] = n;
                    }
                }
        }
    }

    // cross-lane argmin over the 16-col group; ties -> lowest v
#pragma unroll
    for (int off = 1; off < 16; off <<= 1) {
#pragma unroll
        for (int mt = 0; mt < 4; ++mt)
#pragma unroll
            for (int r = 0; r < 4; ++r) {
                const float of = __shfl_xor(bestF[mt][r], off, 64);
                const int ov = __shfl_xor(bestv[mt][r], off, 64);
                if (of < bestF[mt][r] || (of == bestF[mt][r] && ov < bestv[mt][r])) {
                    bestF[mt][r] = of;
                    bestv[mt][r] = ov;
                }
            }
    }

    if (ln == 0) {
#pragma unroll
        for (int mt = 0; mt < 4; ++mt)
#pragma unroll
            for (int r = 0; r < 4; ++r) {
                const int m = mt * 16 + q * 4 + r;
                sbest[wq][m] = bestF[mt][r];
                sbv[wq][m] = bestv[mt][r];
            }
    }
    __syncthreads();

    if (tid < 64) {
        float bb = sbest[0][tid];
        int bv = sbv[0][tid];
#pragma unroll
        for (int w = 1; w < 4; ++w) {
            const float of = sbest[w][tid];
            const int ov = sbv[w][tid];
            if (of < bb) {  // waves ascend in v; strict < keeps lowest v on ties
                bb = of;
                bv = ov;
            }
        }
        scode[tid] = bv;
        out_codes[(size_t)b * T_ + t00 + tid] = (float)bv;
    }
    __syncthreads();

    // gather-write quantized[b, d, t00+tl] = codebook[code, d]; coalesced stores
    const int code = scode[tl];
    const float* crow = codebook + (size_t)code * D_;
    float* qp = out_q + (size_t)b * D_ * T_ + t00 + tl;
#pragma unroll
    for (int i = 0; i < 32; ++i) {
        const int d = wq * 32 + i;
        qp[(size_t)d * T_] = crow[d];
    }
}

extern "C" void kernel_launch(void* const* d_in, const int* in_sizes, int n_in,
                              void* d_out, int out_size, void* d_ws, size_t ws_size,
                              hipStream_t stream) {
    const float* latents = (const float*)d_in[0];   // (B, D, T) f32
    const float* codebook = (const float*)d_in[1];  // (V, D) f32

    float* out_codes = (float*)d_out;        // (B, T) codes as f32 values
    float* out_q = (float*)d_out + B_ * T_;  // (B, D, T) quantized f32

    float* chsq = (float*)d_ws;
    _Float16* Bh = (_Float16*)((char*)d_ws + 4096);
    _Float16* Bl = (_Float16*)((char*)d_ws + 4096 + 262144);

    split_csq_kernel<<<(V_ * 16) / 256, 256, 0, stream>>>(codebook, Bh, Bl, chsq);
    vq_mfma<<<(B_ * T_) / 64, 256, 0, stream>>>(latents, codebook, chsq, Bh, Bl, out_codes,
                                                out_q);
}

// Round 8
// 130.290 us; speedup vs baseline: 3.6616x; 1.1875x over previous
//
#include <hip/hip_runtime.h>

// (B, D, T, V) = (16, 128, 4096, 1024)
#define B_ 16
#define D_ 128
#define T_ 4096
#define V_ 1024

typedef _Float16 half8 __attribute__((ext_vector_type(8)));
typedef float float4v __attribute__((ext_vector_type(4)));

// ws layout:
//   [0,       4096)   : chsq (V floats) = 0.5*|c|^2
//   [4096,  266240)   : Bh   (4 kt x 1024 v x 32 kk) f16 hi split; byte addr =
//                        kt*65536 + v*64 + kk*2  (2KB contiguous per (kt, 32v-chunk))
//   [266240,528384)   : Bl   (same, lo split scaled by 2048)
//
// LESSONS:
//  R3/R4: forcing __launch_bounds__(256,{3,4}) spills through HBM (FETCH
//    356-853MB signature). Stay at (256,2).
//  R5: hipLaunchCooperativeKernel fails under this harness.
//  R6: occupancy can't be raised honestly; hide latency with ILP/data-flow.
//  R7: B software-pipeline 109->88us, but waves-split-v re-reads A from LDS 8x
//    and loads B privately -> per-wave serial chains ~= measured time.
//  R8: waves split t; B block-shared via global_load_lds dbuf; A in registers.

// Fused: split codebook into f16 hi/lo fragments AND compute chsq.
__global__ __launch_bounds__(256) void split_csq_kernel(const float* __restrict__ cb,
                                                        _Float16* __restrict__ Bh,
                                                        _Float16* __restrict__ Bl,
                                                        float* __restrict__ chsq) {
    const int g = blockIdx.x * 256 + threadIdx.x;  // 16384 threads
    const int v = g >> 4;
    const int k0 = (g & 15) << 3;
    const float* src = cb + (size_t)v * D_ + k0;
    half8 h, l;
    float s = 0.f;
#pragma unroll
    for (int j = 0; j < 8; ++j) {
        float c = src[j];
        _Float16 ch = (_Float16)c;
        h[j] = ch;
        l[j] = (_Float16)((c - (float)ch) * 2048.0f);
        s = fmaf(c, c, s);
    }
    const int kt = k0 >> 5;
    const int kk = k0 & 31;
    const size_t off = ((size_t)(kt * V_ + v)) * 32 + kk;
    *(half8*)(Bh + off) = h;
    *(half8*)(Bl + off) = l;
#pragma unroll
    for (int o = 1; o < 16; o <<= 1) s += __shfl_xor(s, o, 64);
    if ((g & 15) == 0) chsq[v] = 0.5f * s;
}

// Async 16B/lane global->LDS copy. lds must be wave-uniform; HW scatters
// lane i to lds + i*16. [guide m97: emits global_load_lds_dwordx4]
__device__ __forceinline__ void dma16(const char* g, char* lds) {
    __builtin_amdgcn_global_load_lds(
        (const __attribute__((address_space(1))) unsigned int*)g,
        (__attribute__((address_space(3))) unsigned int*)lds, 16, 0, 0);
}

// Stage one 32-v chunk (16 KB: Bh 8KB + Bl 8KB) into ldsbuf.
// seg = wq*4+j in [0,16): bits [3]=h/l, [2:1]=kt, [0]=which 1KB of the 2KB slice.
__device__ __forceinline__ void dma_chunk(char* ldsbuf, const char* BhB, const char* BlB,
                                          int c, int wq, int tl) {
#pragma unroll
    for (int j = 0; j < 4; ++j) {
        const int seg = wq * 4 + j;
        const int hl = seg >> 3;
        const int kt = (seg >> 1) & 3;
        const int o1k = seg & 1;
        const char* src = (hl ? BlB : BhB) + kt * 65536 + c * 2048 + o1k * 1024 + tl * 16;
        dma16(src, ldsbuf + seg * 1024);
    }
}

// Main kernel: block = 256 thr = 4 waves; block tile = 128 t x all 1024 v.
// Wave wq owns t-rows [wq*32, wq*32+32) (mt=2); ALL waves sweep ALL v in 32
// chunks of 32 v, reading block-shared B fragments from an LDS double-buffer
// filled by async DMA one chunk ahead. A fragments live in registers (64 VGPR,
// extracted once). Dual accumulators (numerics proven, absmax 0):
//   acc1 = sum_k xh*ch ; acc2 = sum_k (xh*cl' + xl'*ch)   (lo pre-scaled 2048)
//   score = 0.5|c|^2 - (acc1 + acc2/2048); running argmin, ties -> lowest v.
__global__ __launch_bounds__(256, 2) void vq_mfma(const float* __restrict__ latents,
                                                  const float* __restrict__ codebook,
                                                  const float* __restrict__ chsq,
                                                  const _Float16* __restrict__ Bh,
                                                  const _Float16* __restrict__ Bl,
                                                  float* __restrict__ out_codes,
                                                  float* __restrict__ out_q) {
    // union: A-stage (128x136 x2 halves = 69632 B) then B double-buffer (2x16384)
    __shared__ __align__(16) char smem[69632];
    __shared__ float sChsq[V_];
    __shared__ int scode[128];

    const int tid = threadIdx.x;
    const int tl = tid & 63;
    const int wq = tid >> 6;
    const int ln = tid & 15;       // MFMA col (n) / A row (m)
    const int q = (tid >> 4) & 3;  // quad
    const int b = blockIdx.x >> 5;           // 32 t-tiles of 128 per batch entry
    const int t00 = (blockIdx.x & 31) << 7;  // t-tile start

    _Float16* AhS = (_Float16*)smem;  // [128][136] (+8 pad)
    _Float16* AlS = AhS + 128 * 136;

    // ---- stage chsq into LDS ----
#pragma unroll
    for (int i = 0; i < V_ / 256; ++i) sChsq[tid + i * 256] = chsq[tid + i * 256];

    // ---- stage A tile (128 t x 128 d), f16 split, [t][k] rows ----
#pragma unroll
    for (int th = 0; th < 2; ++th) {
        const int row = th * 64 + tl;
        const float* xp = latents + (size_t)b * D_ * T_ + t00 + row;
#pragma unroll
        for (int i = 0; i < 4; ++i) {
            const int d0 = wq * 32 + i * 8;
            float x[8];
#pragma unroll
            for (int j = 0; j < 8; ++j) x[j] = xp[(size_t)(d0 + j) * T_];
            half8 h, l;
#pragma unroll
            for (int j = 0; j < 8; ++j) {
                _Float16 xh = (_Float16)x[j];
                h[j] = xh;
                l[j] = (_Float16)((x[j] - (float)xh) * 2048.0f);
            }
            *(half8*)(AhS + row * 136 + d0) = h;
            *(half8*)(AlS + row * 136 + d0) = l;
        }
    }
    __syncthreads();

    // ---- extract A fragments to registers (once): wave owns rows wq*32..+32 ----
    half8 ah[4][2], al[4][2];  // [kt][mt] : 64 VGPRs
#pragma unroll
    for (int kt = 0; kt < 4; ++kt)
#pragma unroll
        for (int mt = 0; mt < 2; ++mt) {
            const int row = wq * 32 + mt * 16 + ln;
            ah[kt][mt] = *(const half8*)(AhS + row * 136 + kt * 32 + q * 8);
            al[kt][mt] = *(const half8*)(AlS + row * 136 + kt * 32 + q * 8);
        }
    __syncthreads();  // A region dead -> reuse as B double-buffer

    char* Bb = smem;  // [2][16384]
    const char* BhB = (const char*)Bh;
    const char* BlB = (const char*)Bl;

    float bestF[2][4];
    int bestv[2][4];
#pragma unroll
    for (int mt = 0; mt < 2; ++mt)
#pragma unroll
        for (int r = 0; r < 4; ++r) {
            bestF[mt][r] = 3.0e38f;
            bestv[mt][r] = 0;
        }

    // ---- prologue: DMA chunk 0 into buf 0; barrier drains vmcnt ----
    dma_chunk(Bb, BhB, BlB, 0, wq, tl);
    __syncthreads();

    for (int c = 0; c < 32; ++c) {
        // prefetch next chunk into the other buffer; its readers (chunk c-1)
        // all passed the previous barrier, and the end-of-iteration barrier
        // drains it after ~600 cyc of compute cover.
        if (c + 1 < 32) dma_chunk(Bb + ((c + 1) & 1) * 16384, BhB, BlB, c + 1, wq, tl);

        const char* buf = Bb + (c & 1) * 16384;
        float4v acc1[2][2], acc2[2][2];
#pragma unroll
        for (int mt = 0; mt < 2; ++mt)
#pragma unroll
            for (int ntl = 0; ntl < 2; ++ntl) {
                acc1[mt][ntl] = (float4v){0.f, 0.f, 0.f, 0.f};
                acc2[mt][ntl] = (float4v){0.f, 0.f, 0.f, 0.f};
            }
#pragma unroll
        for (int kt = 0; kt < 4; ++kt) {
            half8 bh[2], bl[2];
#pragma unroll
            for (int ntl = 0; ntl < 2; ++ntl) {
                const int o = kt * 2048 + (ntl * 16 + ln) * 64 + q * 16;
                bh[ntl] = *(const half8*)(buf + o);
                bl[ntl] = *(const half8*)(buf + 8192 + o);
            }
#pragma unroll
            for (int ntl = 0; ntl < 2; ++ntl)
#pragma unroll
                for (int mt = 0; mt < 2; ++mt) {
                    acc1[mt][ntl] = __builtin_amdgcn_mfma_f32_16x16x32_f16(
                        ah[kt][mt], bh[ntl], acc1[mt][ntl], 0, 0, 0);
                    acc2[mt][ntl] = __builtin_amdgcn_mfma_f32_16x16x32_f16(
                        ah[kt][mt], bl[ntl], acc2[mt][ntl], 0, 0, 0);
                    acc2[mt][ntl] = __builtin_amdgcn_mfma_f32_16x16x32_f16(
                        al[kt][mt], bh[ntl], acc2[mt][ntl], 0, 0, 0);
                }
        }
        // fold scores into running argmin (ntl=0 first: lower n wins ties)
#pragma unroll
        for (int ntl = 0; ntl < 2; ++ntl) {
            const int n = c * 32 + ntl * 16 + ln;
            const float csq = sChsq[n];
#pragma unroll
            for (int mt = 0; mt < 2; ++mt)
#pragma unroll
                for (int r = 0; r < 4; ++r) {
                    const float score =
                        csq - (acc1[mt][ntl][r] + acc2[mt][ntl][r] * (1.0f / 2048.0f));
                    if (score < bestF[mt][r]) {  // strict < => lowest v on ties
                        bestF[mt][r] = score;
                        bestv[mt][r] = n;
                    }
                }
        }
        __syncthreads();  // drain DMA(c+1) + release buf[c&1] for chunk c+2
    }

    // cross-lane argmin over the 16-col group; ties -> lowest v
#pragma unroll
    for (int off = 1; off < 16; off <<= 1) {
#pragma unroll
        for (int mt = 0; mt < 2; ++mt)
#pragma unroll
            for (int r = 0; r < 4; ++r) {
                const float of = __shfl_xor(bestF[mt][r], off, 64);
                const int ov = __shfl_xor(bestv[mt][r], off, 64);
                if (of < bestF[mt][r] || (of == bestF[mt][r] && ov < bestv[mt][r])) {
                    bestF[mt][r] = of;
                    bestv[mt][r] = ov;
                }
            }
    }

    // per-wave complete argmin: lanes ln==0 publish rows m = wq*32+mt*16+q*4+r
    if (ln == 0) {
#pragma unroll
        for (int mt = 0; mt < 2; ++mt)
#pragma unroll
            for (int r = 0; r < 4; ++r) {
                const int m = wq * 32 + mt * 16 + q * 4 + r;
                scode[m] = bestv[mt][r];
                out_codes[(size_t)b * T_ + t00 + m] = (float)bestv[mt][r];
            }
    }
    __syncthreads();

    // gather-write quantized[b, d, t00+row] = codebook[code, d]; coalesced
#pragma unroll
    for (int th = 0; th < 2; ++th) {
        const int row = th * 64 + tl;
        const int code = scode[row];
        const float* crow = codebook + (size_t)code * D_;
        float* qp = out_q + (size_t)b * D_ * T_ + t00 + row;
#pragma unroll
        for (int i = 0; i < 32; ++i) {
            const int d = wq * 32 + i;
            qp[(size_t)d * T_] = crow[d];
        }
    }
}

extern "C" void kernel_launch(void* const* d_in, const int* in_sizes, int n_in,
                              void* d_out, int out_size, void* d_ws, size_t ws_size,
                              hipStream_t stream) {
    const float* latents = (const float*)d_in[0];   // (B, D, T) f32
    const float* codebook = (const float*)d_in[1];  // (V, D) f32

    float* out_codes = (float*)d_out;        // (B, T) codes as f32 values
    float* out_q = (float*)d_out + B_ * T_;  // (B, D, T) quantized f32

    float* chsq = (float*)d_ws;
    _Float16* Bh = (_Float16*)((char*)d_ws + 4096);
    _Float16* Bl = (_Float16*)((char*)d_ws + 4096 + 262144);

    split_csq_kernel<<<(V_ * 16) / 256, 256, 0, stream>>>(codebook, Bh, Bl, chsq);
    vq_mfma<<<(B_ * T_) / 128, 256, 0, stream>>>(latents, codebook, chsq, Bh, Bl,
                                                 out_codes, out_q);
}